// Round 15
// baseline (161.277 us; speedup 1.0000x reference)
//
#include <hip/hip_runtime.h>
#include <math.h>

#define NQ    64
#define DIM   256
#define SEQ   128
#define CAP   500000
#define TOPK  5
#define KT    32                 // keys per tile
#define NTILE (CAP / KT)         // 15625 exact
#define NBLK  768                // 3 blocks/CU * 256 CU
#define PB    7                  // per-block per-query candidates
#define NC    (NBLK * PB)        // 5376 candidates per query
#define DELTA 3.0e-3f            // bf16-sim + bf16-norm safety margin
#define MAXC  192

typedef short short8v __attribute__((ext_vector_type(8)));
typedef float f32x4   __attribute__((ext_vector_type(4)));

// barrier WITHOUT vmcnt drain: LDS-drain + raw s_barrier + compiler fence.
#define SYNC_NODRAIN() do {                                        \
    asm volatile("s_waitcnt lgkmcnt(0)" ::: "memory");             \
    __builtin_amdgcn_s_barrier();                                  \
    asm volatile("" ::: "memory"); } while (0)

__device__ inline unsigned pkbf(float a, float b) {   // 2x fp32 -> packed bf16 (RNE)
    unsigned ua = __builtin_bit_cast(unsigned, a);
    unsigned ub = __builtin_bit_cast(unsigned, b);
    ua = (ua + 0x7fffu + ((ua >> 16) & 1u)) >> 16;
    ub = (ub + 0x7fffu + ((ub >> 16) & 1u)) >> 16;
    return ua | (ub << 16);
}

// ------- Kernel A1: query partial sums (4 chunks of S) + counts copy --------
__global__ void qmean_part_kernel(const float* __restrict__ query,
                                  const float* __restrict__ ac,
                                  float* __restrict__ qpart,
                                  float* __restrict__ outCnt) {
    int blk = blockIdx.x;          // 256
    int d = threadIdx.x;           // 256
    int b = blk >> 2, ch = blk & 3;
    const float* qb = query + ((size_t)b * SEQ + ch * 32) * DIM;
    float s = 0.f;
    #pragma unroll 4
    for (int t = 0; t < 32; ++t) s += qb[(size_t)t * DIM + d];
    qpart[blk * DIM + d] = s;
    for (int i = blk * 256 + d; i < CAP / 4; i += 256 * 256)
        ((float4*)outCnt)[i] = ((const float4*)ac)[i];
}

// ------- Kernel A2: combine partials, mean, L2 normalize --------------------
__global__ void qmean_norm2_kernel(const float* __restrict__ qpart,
                                   float* __restrict__ qn) {
    int b = blockIdx.x;            // 64
    int d = threadIdx.x;           // 256
    float s = qpart[(b * 4 + 0) * DIM + d] + qpart[(b * 4 + 1) * DIM + d]
            + qpart[(b * 4 + 2) * DIM + d] + qpart[(b * 4 + 3) * DIM + d];
    float m = s * (1.0f / SEQ);
    float ss = m * m;
    #pragma unroll
    for (int off = 32; off > 0; off >>= 1) ss += __shfl_down(ss, off, 64);
    __shared__ float red[4];
    if ((threadIdx.x & 63) == 0) red[threadIdx.x >> 6] = ss;
    __syncthreads();
    float tot = red[0] + red[1] + red[2] + red[3];
    float r = 1.0f / fmaxf(sqrtf(tot), 1e-12f);
    qn[b * DIM + d] = m * r;
}

// ---------------- Kernel B: bf16-MFMA sims + per-block top-7 ----------------
// Round-14 champion + depth-2 staging: two 32-VGPR slots, consume-and-reissue
// at 3N distance (vmcnt(8) leaves the other slot in flight -> ~64KB/block
// continuously). Funded by 3 blocks/CU (VGPR ceiling 170 at 3 waves/SIMD).
__global__ __launch_bounds__(256, 3) void sims_mfma_topk(
        const float* __restrict__ keys, const float* __restrict__ qn,
        float* __restrict__ candV, int* __restrict__ candI) {
    __shared__ __align__(16) unsigned short kb[2][KT * DIM];  // 2 x 16 KB, swizzled

    const int tid  = threadIdx.x;
    const int lane = tid & 63;
    const int wave = tid >> 6;
    const int key0 = lane & 15;
    const int g    = lane >> 4;        // k-chunk group 0..3
    const int kl3  = key0 & 7;

    // ---- A fragments: wave's 16 queries, K=256 -> 8 steps, bf16 in regs ----
    short8v afr[8];
    {
        const float* qrow = qn + ((wave << 4) + key0) * DIM;
        int kbase = g * 8;
        #pragma unroll
        for (int st = 0; st < 8; ++st) {
            float4 a = *(const float4*)(qrow + st * 32 + kbase);
            float4 b = *(const float4*)(qrow + st * 32 + kbase + 4);
            uint4 w;
            w.x = pkbf(a.x, a.y); w.y = pkbf(a.z, a.w);
            w.z = pkbf(b.x, b.y); w.w = pkbf(b.z, b.w);
            afr[st] = __builtin_bit_cast(short8v, w);
        }
    }

    float tv[PB]; int ti[PB];
    #pragma unroll
    for (int p = 0; p < PB; ++p) { tv[p] = -INFINITY; ti[p] = 0; }

    // ---- staging: wave-contiguous, NONTEMPORAL, two slots ----
    f32x4 s0[8], s1[8];
    auto issue_into = [&](f32x4 (&dst)[8], int tile) {
        const f32x4* src = (const f32x4*)(keys + (size_t)tile * KT * DIM
                         + (size_t)(wave * 8) * DIM) + lane;
        #pragma unroll
        for (int j = 0; j < 8; ++j)
            dst[j] = __builtin_nontemporal_load(src + j * (DIM / 4));
    };
    // row = wave*8+j (row&7 == j), dims [lane*4, lane*4+4); swizzled 16B slots.
    auto write_stage_from = [&](int buf, f32x4 (&stg)[8]) {
        char* kc = (char*)&kb[buf][0];
        #pragma unroll
        for (int j = 0; j < 8; ++j) {
            uint2 pk;
            pk.x = pkbf(stg[j][0], stg[j][1]);
            pk.y = pkbf(stg[j][2], stg[j][3]);
            unsigned dst = (unsigned)((wave * 8 + j) * 512
                                      + ((lane * 8) ^ (j << 4)));
            *(uint2*)(kc + dst) = pk;
        }
    };

    // one tile iteration; kb[cur] = tile data, sc = slot holding tile+NBLK.
    // Consume sc (vmcnt(8): other slot stays in flight), reissue sc <- tile+3N.
    auto body = [&](int tile, int cur, f32x4 (&sc)[8]) {
        f32x4 acc0  = {0.f, 0.f, 0.f, 0.f}, acc1  = {0.f, 0.f, 0.f, 0.f};
        f32x4 acck0 = {0.f, 0.f, 0.f, 0.f}, acck1 = {0.f, 0.f, 0.f, 0.f};
        const char* kc = (const char*)&kb[cur][0];
        #pragma unroll
        for (int st = 0; st < 8; ++st) {
            unsigned Xs = ((unsigned)(st * 64 + g * 16)) ^ (kl3 << 4);
            short8v b0 = *(const short8v*)(kc + key0 * 512 + Xs);
            short8v b1 = *(const short8v*)(kc + key0 * 512 + 8192 + Xs);
            acc0  = __builtin_amdgcn_mfma_f32_16x16x32_bf16(afr[st], b0, acc0, 0, 0, 0);
            acc1  = __builtin_amdgcn_mfma_f32_16x16x32_bf16(afr[st], b1, acc1, 0, 0, 0);
            acck0 = __builtin_amdgcn_mfma_f32_16x16x32_bf16(b0, b0, acck0, 0, 0, 0);
            acck1 = __builtin_amdgcn_mfma_f32_16x16x32_bf16(b1, b1, acck1, 0, 0, 0);
        }
        // diag |k|^2 of key j sits at lane ((j>>2)<<4)+j, reg j&3
        float dv0 = (key0 & 2) ? ((key0 & 1) ? acck0[3] : acck0[2])
                               : ((key0 & 1) ? acck0[1] : acck0[0]);
        float dv1 = (key0 & 2) ? ((key0 & 1) ? acck1[3] : acck1[2])
                               : ((key0 & 1) ? acck1[1] : acck1[0]);
        int src = ((key0 >> 2) << 4) + key0;
        float rk0 = __shfl(rsqrtf(fmaxf(dv0, 1e-24f)), src, 64);
        float rk1 = __shfl(rsqrtf(fmaxf(dv1, 1e-24f)), src, 64);
        SYNC_NODRAIN();   // all waves done reading kb[cur]; prev scan done

        // sims aliased into the just-consumed kb[cur]; [64][33] f32 layout.
        float* simsp = (float*)&kb[cur][0];
        {
            int q0 = (wave << 4) + (g << 2);
            #pragma unroll
            for (int r = 0; r < 4; ++r) {
                simsp[(q0 + r) * 33 + key0]      = acc0[r] * rk0;
                simsp[(q0 + r) * 33 + 16 + key0] = acc1[r] * rk1;
            }
        }
        if (tile + NBLK < NTILE) write_stage_from(cur ^ 1, sc);   // vmcnt(8) here
        if (tile + 3 * NBLK < NTILE) issue_into(sc, tile + 3 * NBLK);
        SYNC_NODRAIN();   // sims ready; kb[cur^1] staged

        // top-PB update: lane = query, wave scans its 8 key slots
        #pragma unroll
        for (int ks = 0; ks < 8; ++ks) {
            int ko = (wave << 3) + ks;
            float v = simsp[lane * 33 + ko];
            if (v > tv[PB - 1]) {
                tv[PB - 1] = v; ti[PB - 1] = tile * KT + ko;
                #pragma unroll
                for (int p = PB - 1; p > 0; --p) {
                    if (tv[p] > tv[p - 1]) {
                        float fv = tv[p]; tv[p] = tv[p - 1]; tv[p - 1] = fv;
                        int   fi = ti[p]; ti[p] = ti[p - 1]; ti[p - 1] = fi;
                    }
                }
            }
        }
    };

    // prologue: kb[0] <- t0; s1 <- t0+N; s0 <- t0+2N (max 2303 < NTILE)
    int tile = blockIdx.x;
    issue_into(s0, tile);
    write_stage_from(0, s0);
    issue_into(s1, tile + NBLK);
    issue_into(s0, tile + 2 * NBLK);
    SYNC_NODRAIN();

    int cur = 0;
    while (true) {
        body(tile, cur, s1);           // consume s1 (t+N), reissue s1 (t+3N)
        tile += NBLK; cur ^= 1;
        if (tile >= NTILE) break;
        body(tile, cur, s0);           // consume s0 (t+N), reissue s0 (t+3N)
        tile += NBLK; cur ^= 1;
        if (tile >= NTILE) break;
    }

    // ---- per-block merge: 4 wave-lists of PB -> top-PB per query ----
    __syncthreads();
    float* mv = (float*)&kb[0][0];
    int*   mi = (int*)&kb[0][0] + 2048;
    {
        int base = (wave * 64 + lane) * PB;
        #pragma unroll
        for (int p = 0; p < PB; ++p) { mv[base + p] = tv[p]; mi[base + p] = ti[p]; }
    }
    __syncthreads();
    if (wave == 0) {
        float fv[PB]; int fi[PB];
        #pragma unroll
        for (int p = 0; p < PB; ++p) { fv[p] = -INFINITY; fi[p] = 0; }
        for (int w = 0; w < 4; ++w) {
            #pragma unroll
            for (int p = 0; p < PB; ++p) {
                float v = mv[(w * 64 + lane) * PB + p];
                int  id = mi[(w * 64 + lane) * PB + p];
                if (v > fv[PB - 1]) {
                    fv[PB - 1] = v; fi[PB - 1] = id;
                    #pragma unroll
                    for (int p2 = PB - 1; p2 > 0; --p2) {
                        if (fv[p2] > fv[p2 - 1]) {
                            float a = fv[p2]; fv[p2] = fv[p2 - 1]; fv[p2 - 1] = a;
                            int   c = fi[p2]; fi[p2] = fi[p2 - 1]; fi[p2 - 1] = c;
                        }
                    }
                }
            }
        }
        size_t cb = ((size_t)lane * NBLK + blockIdx.x) * PB;
        #pragma unroll
        for (int p = 0; p < PB; ++p) { candV[cb + p] = fv[p]; candI[cb + p] = fi[p]; }
    }
}

// ---- Kernel C: global bf16-top5 -> threshold select -> exact fp32 rescore ----
__global__ void finalize_kernel(const float* __restrict__ candV,
                                const int* __restrict__ candI,
                                const float* __restrict__ keys,
                                const float* __restrict__ qn,
                                const float* __restrict__ values,
                                float* __restrict__ outRet,
                                float* __restrict__ outCnt) {
    const int b = blockIdx.x;      // query
    const int t = threadIdx.x;     // 256
    const int lane = t & 63, wave = t >> 6;
    __shared__ float rv[256]; __shared__ int rp[256];
    __shared__ int   chosen[TOPK];
    __shared__ float v5s;
    __shared__ int   clist[MAXC];
    __shared__ float rsc[MAXC];
    __shared__ int   ccnt;
    __shared__ float qs[DIM];
    __shared__ int   kidx[TOPK];

    const float* cv = candV + (size_t)b * NC;
    const int*   ci = candI + (size_t)b * NC;

    // phase 1: 5 argmax passes over bf16-sims -> v5 (5th largest)
    for (int pass = 0; pass < TOPK; ++pass) {
        float lv = -INFINITY; int lp = 0x7fffffff;
        for (int m = t; m < NC; m += 256) {
            bool skip = false;
            for (int k2 = 0; k2 < pass; ++k2) skip |= (m == chosen[k2]);
            float v = cv[m];
            if (!skip && (v > lv || (v == lv && m < lp))) { lv = v; lp = m; }
        }
        rv[t] = lv; rp[t] = lp;
        __syncthreads();
        for (int s = 128; s > 0; s >>= 1) {
            if (t < s) {
                if (rv[t + s] > rv[t] || (rv[t + s] == rv[t] && rp[t + s] < rp[t])) {
                    rv[t] = rv[t + s]; rp[t] = rp[t + s];
                }
            }
            __syncthreads();
        }
        if (t == 0) { chosen[pass] = rp[0]; if (pass == TOPK - 1) v5s = rv[0]; }
        __syncthreads();
    }

    // phase 2: collect candidates >= v5 - DELTA (provable superset of true top5)
    if (t == 0) ccnt = 0;
    __syncthreads();
    float thr = v5s - DELTA;
    for (int m = t; m < NC; m += 256) {
        if (cv[m] >= thr) {
            int pos = atomicAdd(&ccnt, 1);
            if (pos < MAXC) clist[pos] = ci[m];
        }
    }
    qs[t] = qn[b * DIM + t];
    __syncthreads();
    int cnt = min(ccnt, MAXC);

    // phase 3: exact fp32 rescore (one wave per candidate)
    for (int c = wave; c < cnt; c += 4) {
        const float4 k4 = *(const float4*)(keys + (size_t)clist[c] * DIM + lane * 4);
        const float4 q4 = *(const float4*)(qs + lane * 4);
        float d  = q4.x * k4.x + q4.y * k4.y + q4.z * k4.z + q4.w * k4.w;
        float s2 = k4.x * k4.x + k4.y * k4.y + k4.z * k4.z + k4.w * k4.w;
        #pragma unroll
        for (int off = 1; off < 64; off <<= 1) {
            d  += __shfl_xor(d, off, 64);
            s2 += __shfl_xor(s2, off, 64);
        }
        if (lane == 0) rsc[c] = d * rsqrtf(fmaxf(s2, 1e-24f));
    }
    __syncthreads();

    // phase 4: exact top-5 among rescored candidates
    for (int pass = 0; pass < TOPK; ++pass) {
        float lv = -INFINITY; int lp = 0x7fffffff;
        if (t < cnt) {
            bool skip = false;
            for (int k2 = 0; k2 < pass; ++k2) skip |= (t == chosen[k2]);
            if (!skip) { lv = rsc[t]; lp = t; }
        }
        rv[t] = lv; rp[t] = lp;
        __syncthreads();
        for (int s = 128; s > 0; s >>= 1) {
            if (t < s) {
                if (rv[t + s] > rv[t] || (rv[t + s] == rv[t] && rp[t + s] < rp[t])) {
                    rv[t] = rv[t + s]; rp[t] = rp[t + s];
                }
            }
            __syncthreads();
        }
        if (t == 0) { chosen[pass] = rp[0]; kidx[pass] = clist[rp[0]]; }
        __syncthreads();
    }

    // phase 5: gather values + mean; scatter counts
    float s = 0.f;
    #pragma unroll
    for (int p = 0; p < TOPK; ++p) s += values[(size_t)kidx[p] * DIM + t];
    outRet[b * DIM + t] = s * 0.2f;
    if (t < TOPK) atomicAdd(&outCnt[kidx[t]], 1.0f);
}

// ---------------- launch -----------------------------------------------------
extern "C" void kernel_launch(void* const* d_in, const int* in_sizes, int n_in,
                              void* d_out, int out_size, void* d_ws, size_t ws_size,
                              hipStream_t stream) {
    const float* query  = (const float*)d_in[0];
    const float* keys   = (const float*)d_in[1];
    const float* values = (const float*)d_in[2];
    const float* acnt   = (const float*)d_in[3];
    float* outRet = (float*)d_out;
    float* outCnt = outRet + NQ * DIM;

    char* ws = (char*)d_ws;
    float* qn    = (float*)ws;                                   // 64 KB
    float* qpart = (float*)(ws + 65536);                         // 256 KB
    float* candV = (float*)(ws + 65536 + 262144);                // 1.31 MB
    int*   candI = (int*)(ws + 65536 + 262144 + (size_t)NQ * NC * 4);

    qmean_part_kernel<<<256, 256, 0, stream>>>(query, acnt, qpart, outCnt);
    qmean_norm2_kernel<<<NQ, 256, 0, stream>>>(qpart, qn);
    sims_mfma_topk<<<NBLK, 256, 0, stream>>>(keys, qn, candV, candI);
    finalize_kernel<<<NQ, 256, 0, stream>>>(candV, candI, keys, qn, values,
                                            outRet, outCnt);
}

// Round 16
// 157.807 us; speedup vs baseline: 1.0220x; 1.0220x over previous
//
#include <hip/hip_runtime.h>
#include <math.h>

#define NQ    64
#define DIM   256
#define SEQ   128
#define CAP   500000
#define TOPK  5
#define KT    32
#define NTILE (CAP / KT)
#define NBLK  1024
#define PB    5
#define NC    (NBLK * PB)
#define DELTA 8.0e-3f
#define MAXC  192

typedef short short8v __attribute__((ext_vector_type(8)));
typedef float f32x4   __attribute__((ext_vector_type(4)));

#define SYNC_NODRAIN() do {                                        \
    asm volatile("s_waitcnt lgkmcnt(0)" ::: "memory");             \
    __builtin_amdgcn_s_barrier();                                  \
    asm volatile("" ::: "memory"); } while (0)

__device__ inline unsigned pkbf(float a, float b) {
    unsigned ua = __builtin_bit_cast(unsigned, a);
    unsigned ub = __builtin_bit_cast(unsigned, b);
    ua = (ua + 0x7fffu + ((ua >> 16) & 1u)) >> 16;
    ub = (ub + 0x7fffu + ((ub >> 16) & 1u)) >> 16;
    return ua | (ub << 16);
}

__global__ void qmean_part_kernel(const float* __restrict__ query,
                                  const float* __restrict__ ac,
                                  float* __restrict__ qpart,
                                  float* __restrict__ outCnt) {
    int blk = blockIdx.x;
    int d = threadIdx.x;
    int b = blk >> 2, ch = blk & 3;
    const float* qb = query + ((size_t)b * SEQ + ch * 32) * DIM;
    float s = 0.f;
    #pragma unroll 4
    for (int t = 0; t < 32; ++t) s += qb[(size_t)t * DIM + d];
    qpart[blk * DIM + d] = s;
    for (int i = blk * 256 + d; i < CAP / 4; i += 256 * 256)
        ((float4*)outCnt)[i] = ((const float4*)ac)[i];
}

__global__ void qmean_norm2_kernel(const float* __restrict__ qpart,
                                   float* __restrict__ qn) {
    int b = blockIdx.x;
    int d = threadIdx.x;
    float s = qpart[(b * 4 + 0) * DIM + d] + qpart[(b * 4 + 1) * DIM + d]
            + qpart[(b * 4 + 2) * DIM + d] + qpart[(b * 4 + 3) * DIM + d];
    float m = s * (1.0f / SEQ);
    float ss = m * m;
    #pragma unroll
    for (int off = 32; off > 0; off >>= 1) ss += __shfl_down(ss, off, 64);
    __shared__ float red[4];
    if ((threadIdx.x & 63) == 0) red[threadIdx.x >> 6] = ss;
    __syncthreads();
    float tot = red[0] + red[1] + red[2] + red[3];
    float r = 1.0f / fmaxf(sqrtf(tot), 1e-12f);
    qn[b * DIM + d] = m * r;
}

// One barrier per tile: sims in its own bf16 double-buffer (col-XOR swizzled
// [2][64][32], 8 KB; total LDS exactly 40 KB -> 4 blocks/CU). Phase
// {MFMA | sims-write | write_stage | issue} runs unsynchronized.
__global__ __launch_bounds__(256, 4) void sims_mfma_topk(
        const float* __restrict__ keys, const float* __restrict__ qn,
        float* __restrict__ candV, int* __restrict__ candI) {
    __shared__ __align__(16) unsigned short kb[2][KT * DIM];   // 32 KB
    __shared__ unsigned short sims2[2][64][32];                // 8 KB, bf16

    const int tid  = threadIdx.x;
    const int lane = tid & 63;
    const int wave = tid >> 6;
    const int key0 = lane & 15;
    const int g    = lane >> 4;
    const int kl3  = key0 & 7;

    short8v afr[8];
    {
        const float* qrow = qn + ((wave << 4) + key0) * DIM;
        int kbase = g * 8;
        #pragma unroll
        for (int st = 0; st < 8; ++st) {
            float4 a = *(const float4*)(qrow + st * 32 + kbase);
            float4 b = *(const float4*)(qrow + st * 32 + kbase + 4);
            uint4 w;
            w.x = pkbf(a.x, a.y); w.y = pkbf(a.z, a.w);
            w.z = pkbf(b.x, b.y); w.w = pkbf(b.z, b.w);
            afr[st] = __builtin_bit_cast(short8v, w);
        }
    }

    float tv[PB]; int ti[PB];
    #pragma unroll
    for (int p = 0; p < PB; ++p) { tv[p] = -INFINITY; ti[p] = 0; }

    f32x4 s0[8];
    auto issue_into = [&](int tile) {
        const f32x4* src = (const f32x4*)(keys + (size_t)tile * KT * DIM
                         + (size_t)(wave * 8) * DIM) + lane;
        #pragma unroll
        for (int j = 0; j < 8; ++j)
            s0[j] = __builtin_nontemporal_load(src + j * (DIM / 4));
    };
    auto write_stage = [&](int buf) {
        char* kc = (char*)&kb[buf][0];
        #pragma unroll
        for (int j = 0; j < 8; ++j) {
            uint2 pk;
            pk.x = pkbf(s0[j][0], s0[j][1]);
            pk.y = pkbf(s0[j][2], s0[j][3]);
            unsigned dst = (unsigned)((wave * 8 + j) * 512
                                      + ((lane * 8) ^ (j << 4)));
            *(uint2*)(kc + dst) = pk;
        }
    };

    auto body = [&](int tile, int cur) {
        f32x4 acc0  = {0.f, 0.f, 0.f, 0.f}, acc1  = {0.f, 0.f, 0.f, 0.f};
        f32x4 acck0 = {0.f, 0.f, 0.f, 0.f}, acck1 = {0.f, 0.f, 0.f, 0.f};
        const char* kc = (const char*)&kb[cur][0];
        #pragma unroll
        for (int st = 0; st < 8; ++st) {
            unsigned Xs = ((unsigned)(st * 64 + g * 16)) ^ (kl3 << 4);
            short8v b0 = *(const short8v*)(kc + key0 * 512 + Xs);
            short8v b1 = *(const short8v*)(kc + key0 * 512 + 8192 + Xs);
            acc0  = __builtin_amdgcn_mfma_f32_16x16x32_bf16(afr[st], b0, acc0, 0, 0, 0);
            acc1  = __builtin_amdgcn_mfma_f32_16x16x32_bf16(afr[st], b1, acc1, 0, 0, 0);
            acck0 = __builtin_amdgcn_mfma_f32_16x16x32_bf16(b0, b0, acck0, 0, 0, 0);
            acck1 = __builtin_amdgcn_mfma_f32_16x16x32_bf16(b1, b1, acck1, 0, 0, 0);
        }
        float dv0 = (key0 & 2) ? ((key0 & 1) ? acck0[3] : acck0[2])
                               : ((key0 & 1) ? acck0[1] : acck0[0]);
        float dv1 = (key0 & 2) ? ((key0 & 1) ? acck1[3] : acck1[2])
                               : ((key0 & 1) ? acck1[1] : acck1[0]);
        int src = ((key0 >> 2) << 4) + key0;
        float rk0 = __shfl(rsqrtf(fmaxf(dv0, 1e-24f)), src, 64);
        float rk1 = __shfl(rsqrtf(fmaxf(dv1, 1e-24f)), src, 64);

        // sims write: row q, col-XOR swizzle (col ^ (q&7)) — bijective per row
        {
            int q0 = (wave << 4) + (g << 2);
            #pragma unroll
            for (int r = 0; r < 4; ++r) {
                int q = q0 + r;
                unsigned v0 = __builtin_bit_cast(unsigned, acc0[r] * rk0);
                unsigned v1 = __builtin_bit_cast(unsigned, acc1[r] * rk1);
                sims2[cur][q][key0 ^ (q & 7)]        = (unsigned short)(v0 >> 16);
                sims2[cur][q][(16 + key0) ^ (q & 7)] = (unsigned short)(v1 >> 16);
            }
        }
        if (tile + NBLK < NTILE) write_stage(cur ^ 1);   // per-wave vmcnt wait
        if (tile + 2 * NBLK < NTILE) issue_into(tile + 2 * NBLK);
        SYNC_NODRAIN();                                  // single barrier/tile

        #pragma unroll
        for (int ks = 0; ks < 8; ++ks) {
            int ko = (wave << 3) + ks;
            unsigned short us = sims2[cur][lane][ko ^ (lane & 7)];
            float v = __builtin_bit_cast(float, (unsigned)us << 16);
            if (v > tv[PB - 1]) {
                tv[PB - 1] = v; ti[PB - 1] = tile * KT + ko;
                #pragma unroll
                for (int p = PB - 1; p > 0; --p) {
                    if (tv[p] > tv[p - 1]) {
                        float fv = tv[p]; tv[p] = tv[p - 1]; tv[p - 1] = fv;
                        int   fi = ti[p]; ti[p] = ti[p - 1]; ti[p - 1] = fi;
                    }
                }
            }
        }
    };

    int tile = blockIdx.x;
    issue_into(tile);
    write_stage(0);
    issue_into(tile + NBLK);
    SYNC_NODRAIN();

    int cur = 0;
    while (true) {
        body(tile, cur);
        tile += NBLK; cur ^= 1;
        if (tile >= NTILE) break;
    }

    __syncthreads();
    float* mv = (float*)&kb[0][0];
    int*   mi = (int*)&kb[0][0] + 2048;
    {
        int base = (wave * 64 + lane) * PB;
        #pragma unroll
        for (int p = 0; p < PB; ++p) { mv[base + p] = tv[p]; mi[base + p] = ti[p]; }
    }
    __syncthreads();
    if (wave == 0) {
        float fv[PB]; int fi[PB];
        #pragma unroll
        for (int p = 0; p < PB; ++p) { fv[p] = -INFINITY; fi[p] = 0; }
        for (int w = 0; w < 4; ++w) {
            #pragma unroll
            for (int p = 0; p < PB; ++p) {
                float v = mv[(w * 64 + lane) * PB + p];
                int  id = mi[(w * 64 + lane) * PB + p];
                if (v > fv[PB - 1]) {
                    fv[PB - 1] = v; fi[PB - 1] = id;
                    #pragma unroll
                    for (int p2 = PB - 1; p2 > 0; --p2) {
                        if (fv[p2] > fv[p2 - 1]) {
                            float a = fv[p2]; fv[p2] = fv[p2 - 1]; fv[p2 - 1] = a;
                            int   c = fi[p2]; fi[p2] = fi[p2 - 1]; fi[p2 - 1] = c;
                        }
                    }
                }
            }
        }
        size_t cb = ((size_t)lane * NBLK + blockIdx.x) * PB;
        #pragma unroll
        for (int p = 0; p < PB; ++p) { candV[cb + p] = fv[p]; candI[cb + p] = fi[p]; }
    }
}

__global__ void finalize_kernel(const float* __restrict__ candV,
                                const int* __restrict__ candI,
                                const float* __restrict__ keys,
                                const float* __restrict__ qn,
                                const float* __restrict__ values,
                                float* __restrict__ outRet,
                                float* __restrict__ outCnt) {
    const int b = blockIdx.x;
    const int t = threadIdx.x;
    const int lane = t & 63, wave = t >> 6;
    __shared__ float rv[256]; __shared__ int rp[256];
    __shared__ int   chosen[TOPK];
    __shared__ float v5s;
    __shared__ int   clist[MAXC];
    __shared__ float rsc[MAXC];
    __shared__ int   ccnt;
    __shared__ float qs[DIM];
    __shared__ int   kidx[TOPK];

    const float* cv = candV + (size_t)b * NC;
    const int*   ci = candI + (size_t)b * NC;

    for (int pass = 0; pass < TOPK; ++pass) {
        float lv = -INFINITY; int lp = 0x7fffffff;
        for (int m = t; m < NC; m += 256) {
            bool skip = false;
            for (int k2 = 0; k2 < pass; ++k2) skip |= (m == chosen[k2]);
            float v = cv[m];
            if (!skip && (v > lv || (v == lv && m < lp))) { lv = v; lp = m; }
        }
        rv[t] = lv; rp[t] = lp;
        __syncthreads();
        for (int s = 128; s > 0; s >>= 1) {
            if (t < s) {
                if (rv[t + s] > rv[t] || (rv[t + s] == rv[t] && rp[t + s] < rp[t])) {
                    rv[t] = rv[t + s]; rp[t] = rp[t + s];
                }
            }
            __syncthreads();
        }
        if (t == 0) { chosen[pass] = rp[0]; if (pass == TOPK - 1) v5s = rv[0]; }
        __syncthreads();
    }

    if (t == 0) ccnt = 0;
    __syncthreads();
    float thr = v5s - DELTA;
    for (int m = t; m < NC; m += 256) {
        if (cv[m] >= thr) {
            int pos = atomicAdd(&ccnt, 1);
            if (pos < MAXC) clist[pos] = ci[m];
        }
    }
    qs[t] = qn[b * DIM + t];
    __syncthreads();
    int cnt = min(ccnt, MAXC);

    for (int c = wave; c < cnt; c += 4) {
        const float4 k4 = *(const float4*)(keys + (size_t)clist[c] * DIM + lane * 4);
        const float4 q4 = *(const float4*)(qs + lane * 4);
        float d  = q4.x * k4.x + q4.y * k4.y + q4.z * k4.z + q4.w * k4.w;
        float s2 = k4.x * k4.x + k4.y * k4.y + k4.z * k4.z + k4.w * k4.w;
        #pragma unroll
        for (int off = 1; off < 64; off <<= 1) {
            d  += __shfl_xor(d, off, 64);
            s2 += __shfl_xor(s2, off, 64);
        }
        if (lane == 0) rsc[c] = d * rsqrtf(fmaxf(s2, 1e-24f));
    }
    __syncthreads();

    for (int pass = 0; pass < TOPK; ++pass) {
        float lv = -INFINITY; int lp = 0x7fffffff;
        if (t < cnt) {
            bool skip = false;
            for (int k2 = 0; k2 < pass; ++k2) skip |= (t == chosen[k2]);
            if (!skip) { lv = rsc[t]; lp = t; }
        }
        rv[t] = lv; rp[t] = lp;
        __syncthreads();
        for (int s = 128; s > 0; s >>= 1) {
            if (t < s) {
                if (rv[t + s] > rv[t] || (rv[t + s] == rv[t] && rp[t + s] < rp[t])) {
                    rv[t] = rv[t + s]; rp[t] = rp[t + s];
                }
            }
            __syncthreads();
        }
        if (t == 0) { chosen[pass] = rp[0]; kidx[pass] = clist[rp[0]]; }
        __syncthreads();
    }

    float s = 0.f;
    #pragma unroll
    for (int p = 0; p < TOPK; ++p) s += values[(size_t)kidx[p] * DIM + t];
    outRet[b * DIM + t] = s * 0.2f;
    if (t < TOPK) atomicAdd(&outCnt[kidx[t]], 1.0f);
}

extern "C" void kernel_launch(void* const* d_in, const int* in_sizes, int n_in,
                              void* d_out, int out_size, void* d_ws, size_t ws_size,
                              hipStream_t stream) {
    const float* query  = (const float*)d_in[0];
    const float* keys   = (const float*)d_in[1];
    const float* values = (const float*)d_in[2];
    const float* acnt   = (const float*)d_in[3];
    float* outRet = (float*)d_out;
    float* outCnt = outRet + NQ * DIM;

    char* ws = (char*)d_ws;
    float* qn    = (float*)ws;
    float* qpart = (float*)(ws + 65536);
    float* candV = (float*)(ws + 65536 + 262144);
    int*   candI = (int*)(ws + 65536 + 262144 + (size_t)NQ * NC * 4);

    qmean_part_kernel<<<256, 256, 0, stream>>>(query, acnt, qpart, outCnt);
    qmean_norm2_kernel<<<NQ, 256, 0, stream>>>(qpart, qn);
    sims_mfma_topk<<<NBLK, 256, 0, stream>>>(keys, qn, candV, candI);
    finalize_kernel<<<NQ, 256, 0, stream>>>(candV, candI, keys, qn, values,
                                            outRet, outCnt);
}

// Round 17
// 125.659 us; speedup vs baseline: 1.2835x; 1.2558x over previous
//
#include <hip/hip_runtime.h>
#include <math.h>

#define NQ    64
#define DIM   256
#define SEQ   128
#define CAP   500000
#define TOPK  5
#define KT    32                 // keys per tile
#define NTILE (CAP / KT)         // 15625 exact
#define NBLK  1024               // 4 blocks/CU * 256 CU
#define PB    5                  // per-block per-query candidates
#define NC    (NBLK * PB)        // 5120 candidates per query
#define DELTA 3.0e-3f            // bf16-sim + bf16-norm safety margin
#define MAXC  192

typedef short short8v __attribute__((ext_vector_type(8)));
typedef float f32x4   __attribute__((ext_vector_type(4)));

// barrier WITHOUT vmcnt drain: LDS-drain + raw s_barrier + compiler fence.
#define SYNC_NODRAIN() do {                                        \
    asm volatile("s_waitcnt lgkmcnt(0)" ::: "memory");             \
    __builtin_amdgcn_s_barrier();                                  \
    asm volatile("" ::: "memory"); } while (0)

__device__ inline unsigned pkbf(float a, float b) {   // 2x fp32 -> packed bf16 (RNE)
    unsigned ua = __builtin_bit_cast(unsigned, a);
    unsigned ub = __builtin_bit_cast(unsigned, b);
    ua = (ua + 0x7fffu + ((ua >> 16) & 1u)) >> 16;
    ub = (ub + 0x7fffu + ((ub >> 16) & 1u)) >> 16;
    return ua | (ub << 16);
}

// ------- Kernel A1: query partial sums (4 chunks of S) + counts copy --------
__global__ void qmean_part_kernel(const float* __restrict__ query,
                                  const float* __restrict__ ac,
                                  float* __restrict__ qpart,
                                  float* __restrict__ outCnt) {
    int blk = blockIdx.x;          // 256
    int d = threadIdx.x;           // 256
    int b = blk >> 2, ch = blk & 3;
    const float* qb = query + ((size_t)b * SEQ + ch * 32) * DIM;
    float s = 0.f;
    #pragma unroll 4
    for (int t = 0; t < 32; ++t) s += qb[(size_t)t * DIM + d];
    qpart[blk * DIM + d] = s;
    for (int i = blk * 256 + d; i < CAP / 4; i += 256 * 256)
        ((float4*)outCnt)[i] = ((const float4*)ac)[i];
}

// ------- Kernel A2: combine partials, mean, L2 normalize --------------------
__global__ void qmean_norm2_kernel(const float* __restrict__ qpart,
                                   float* __restrict__ qn) {
    int b = blockIdx.x;            // 64
    int d = threadIdx.x;           // 256
    float s = qpart[(b * 4 + 0) * DIM + d] + qpart[(b * 4 + 1) * DIM + d]
            + qpart[(b * 4 + 2) * DIM + d] + qpart[(b * 4 + 3) * DIM + d];
    float m = s * (1.0f / SEQ);
    float ss = m * m;
    #pragma unroll
    for (int off = 32; off > 0; off >>= 1) ss += __shfl_down(ss, off, 64);
    __shared__ float red[4];
    if ((threadIdx.x & 63) == 0) red[threadIdx.x >> 6] = ss;
    __syncthreads();
    float tot = red[0] + red[1] + red[2] + red[3];
    float r = 1.0f / fmaxf(sqrtf(tot), 1e-12f);
    qn[b * DIM + d] = m * r;
}

// ---------------- Kernel B: bf16-MFMA sims + per-block top-5 ----------------
// ROUND-14 CHAMPION, unchanged: NT coalesced loads, depth-1 reissue (t+2N),
// kb[2] dbuf with sims aliased into the just-consumed buffer, self-MFMA norms,
// SYNC_NODRAIN barriers, 4 blocks/CU.
__global__ __launch_bounds__(256, 4) void sims_mfma_topk(
        const float* __restrict__ keys, const float* __restrict__ qn,
        float* __restrict__ candV, int* __restrict__ candI) {
    __shared__ __align__(16) unsigned short kb[2][KT * DIM];  // 2 x 16 KB, swizzled

    const int tid  = threadIdx.x;
    const int lane = tid & 63;
    const int wave = tid >> 6;
    const int key0 = lane & 15;
    const int g    = lane >> 4;        // k-chunk group 0..3
    const int kl3  = key0 & 7;

    // ---- A fragments: wave's 16 queries, K=256 -> 8 steps, bf16 in regs ----
    short8v afr[8];
    {
        const float* qrow = qn + ((wave << 4) + key0) * DIM;
        int kbase = g * 8;
        #pragma unroll
        for (int st = 0; st < 8; ++st) {
            float4 a = *(const float4*)(qrow + st * 32 + kbase);
            float4 b = *(const float4*)(qrow + st * 32 + kbase + 4);
            uint4 w;
            w.x = pkbf(a.x, a.y); w.y = pkbf(a.z, a.w);
            w.z = pkbf(b.x, b.y); w.w = pkbf(b.z, b.w);
            afr[st] = __builtin_bit_cast(short8v, w);
        }
    }

    float tv[PB]; int ti[PB];
    #pragma unroll
    for (int p = 0; p < PB; ++p) { tv[p] = -INFINITY; ti[p] = 0; }

    // ---- staging: wave-contiguous, NONTEMPORAL, one slot ----
    f32x4 s0[8];
    auto issue_into = [&](int tile) {
        const f32x4* src = (const f32x4*)(keys + (size_t)tile * KT * DIM
                         + (size_t)(wave * 8) * DIM) + lane;
        #pragma unroll
        for (int j = 0; j < 8; ++j)
            s0[j] = __builtin_nontemporal_load(src + j * (DIM / 4));
    };
    // row = wave*8+j (row&7 == j), dims [lane*4, lane*4+4); swizzled 16B slots.
    auto write_stage = [&](int buf) {
        char* kc = (char*)&kb[buf][0];
        #pragma unroll
        for (int j = 0; j < 8; ++j) {
            uint2 pk;
            pk.x = pkbf(s0[j][0], s0[j][1]);
            pk.y = pkbf(s0[j][2], s0[j][3]);
            unsigned dst = (unsigned)((wave * 8 + j) * 512
                                      + ((lane * 8) ^ (j << 4)));
            *(uint2*)(kc + dst) = pk;
        }
    };

    // one tile iteration; kb[cur] = tile data, s0 holds tile+NBLK loads.
    auto body = [&](int tile, int cur) {
        f32x4 acc0  = {0.f, 0.f, 0.f, 0.f}, acc1  = {0.f, 0.f, 0.f, 0.f};
        f32x4 acck0 = {0.f, 0.f, 0.f, 0.f}, acck1 = {0.f, 0.f, 0.f, 0.f};
        const char* kc = (const char*)&kb[cur][0];
        #pragma unroll
        for (int st = 0; st < 8; ++st) {
            unsigned Xs = ((unsigned)(st * 64 + g * 16)) ^ (kl3 << 4);
            short8v b0 = *(const short8v*)(kc + key0 * 512 + Xs);
            short8v b1 = *(const short8v*)(kc + key0 * 512 + 8192 + Xs);
            acc0  = __builtin_amdgcn_mfma_f32_16x16x32_bf16(afr[st], b0, acc0, 0, 0, 0);
            acc1  = __builtin_amdgcn_mfma_f32_16x16x32_bf16(afr[st], b1, acc1, 0, 0, 0);
            acck0 = __builtin_amdgcn_mfma_f32_16x16x32_bf16(b0, b0, acck0, 0, 0, 0);
            acck1 = __builtin_amdgcn_mfma_f32_16x16x32_bf16(b1, b1, acck1, 0, 0, 0);
        }
        // diag |k|^2 of key j sits at lane ((j>>2)<<4)+j, reg j&3
        float dv0 = (key0 & 2) ? ((key0 & 1) ? acck0[3] : acck0[2])
                               : ((key0 & 1) ? acck0[1] : acck0[0]);
        float dv1 = (key0 & 2) ? ((key0 & 1) ? acck1[3] : acck1[2])
                               : ((key0 & 1) ? acck1[1] : acck1[0]);
        int src = ((key0 >> 2) << 4) + key0;
        float rk0 = __shfl(rsqrtf(fmaxf(dv0, 1e-24f)), src, 64);
        float rk1 = __shfl(rsqrtf(fmaxf(dv1, 1e-24f)), src, 64);
        SYNC_NODRAIN();   // all waves done reading kb[cur]; prev scan done

        // sims aliased into the just-consumed kb[cur]; [64][33] f32 layout.
        float* simsp = (float*)&kb[cur][0];
        {
            int q0 = (wave << 4) + (g << 2);
            #pragma unroll
            for (int r = 0; r < 4; ++r) {
                simsp[(q0 + r) * 33 + key0]      = acc0[r] * rk0;
                simsp[(q0 + r) * 33 + 16 + key0] = acc1[r] * rk1;
            }
        }
        if (tile + NBLK < NTILE) write_stage(cur ^ 1);     // vmcnt wait here
        if (tile + 2 * NBLK < NTILE) issue_into(tile + 2 * NBLK);
        SYNC_NODRAIN();   // sims ready; kb[cur^1] staged

        // top-PB update: lane = query, wave scans its 8 key slots
        #pragma unroll
        for (int ks = 0; ks < 8; ++ks) {
            int ko = (wave << 3) + ks;
            float v = simsp[lane * 33 + ko];
            if (v > tv[PB - 1]) {
                tv[PB - 1] = v; ti[PB - 1] = tile * KT + ko;
                #pragma unroll
                for (int p = PB - 1; p > 0; --p) {
                    if (tv[p] > tv[p - 1]) {
                        float fv = tv[p]; tv[p] = tv[p - 1]; tv[p - 1] = fv;
                        int   fi = ti[p]; ti[p] = ti[p - 1]; ti[p - 1] = fi;
                    }
                }
            }
        }
    };

    // prologue: kb[0] <- t0; s0 <- t0+NBLK in flight (max 2047 < NTILE)
    int tile = blockIdx.x;
    issue_into(tile);
    write_stage(0);
    issue_into(tile + NBLK);
    SYNC_NODRAIN();

    int cur = 0;
    while (true) {
        body(tile, cur);
        tile += NBLK; cur ^= 1;
        if (tile >= NTILE) break;
    }

    // ---- per-block merge: 4 wave-lists of PB -> top-PB per query ----
    __syncthreads();
    float* mv = (float*)&kb[0][0];
    int*   mi = (int*)&kb[0][0] + 2048;
    {
        int base = (wave * 64 + lane) * PB;
        #pragma unroll
        for (int p = 0; p < PB; ++p) { mv[base + p] = tv[p]; mi[base + p] = ti[p]; }
    }
    __syncthreads();
    if (wave == 0) {
        float fv[PB]; int fi[PB];
        #pragma unroll
        for (int p = 0; p < PB; ++p) { fv[p] = -INFINITY; fi[p] = 0; }
        for (int w = 0; w < 4; ++w) {
            #pragma unroll
            for (int p = 0; p < PB; ++p) {
                float v = mv[(w * 64 + lane) * PB + p];
                int  id = mi[(w * 64 + lane) * PB + p];
                if (v > fv[PB - 1]) {
                    fv[PB - 1] = v; fi[PB - 1] = id;
                    #pragma unroll
                    for (int p2 = PB - 1; p2 > 0; --p2) {
                        if (fv[p2] > fv[p2 - 1]) {
                            float a = fv[p2]; fv[p2] = fv[p2 - 1]; fv[p2 - 1] = a;
                            int   c = fi[p2]; fi[p2] = fi[p2 - 1]; fi[p2 - 1] = c;
                        }
                    }
                }
            }
        }
        size_t cb = ((size_t)lane * NBLK + blockIdx.x) * PB;
        #pragma unroll
        for (int p = 0; p < PB; ++p) { candV[cb + p] = fv[p]; candI[cb + p] = fi[p]; }
    }
}

// ---- Kernel C: lean finalize -------------------------------------------------
// Phase 1: ONE global pass -> per-thread top-5 -> wave shuffle-merge -> v5s
// (only the 5th-largest VALUE matters; phase 2 re-scans all NC vs threshold).
// Phase 4: rank-based exact top-5 (deterministic (value, key) tie-break).
__global__ void finalize_kernel(const float* __restrict__ candV,
                                const int* __restrict__ candI,
                                const float* __restrict__ keys,
                                const float* __restrict__ qn,
                                const float* __restrict__ values,
                                float* __restrict__ outRet,
                                float* __restrict__ outCnt) {
    const int b = blockIdx.x;      // query
    const int t = threadIdx.x;     // 256
    const int lane = t & 63, wave = t >> 6;
    __shared__ float wtop[4][TOPK];
    __shared__ float v5s;
    __shared__ int   clist[MAXC];
    __shared__ float rsc[MAXC];
    __shared__ int   ccnt;
    __shared__ float qs[DIM];
    __shared__ int   kidx[TOPK];

    const float* cv = candV + (size_t)b * NC;
    const int*   ci = candI + (size_t)b * NC;

    // ---- phase 1: single-pass top-5 values -> v5s ----
    float tv[TOPK];
    #pragma unroll
    for (int p = 0; p < TOPK; ++p) tv[p] = -INFINITY;
    for (int m = t; m < NC; m += 256) {
        float v = cv[m];
        if (v > tv[TOPK - 1]) {
            tv[TOPK - 1] = v;
            #pragma unroll
            for (int p = TOPK - 1; p > 0; --p) {
                if (tv[p] > tv[p - 1]) { float a = tv[p]; tv[p] = tv[p - 1]; tv[p - 1] = a; }
            }
        }
    }
    #pragma unroll
    for (int off = 1; off < 64; off <<= 1) {
        float ov[TOPK];
        #pragma unroll
        for (int p = 0; p < TOPK; ++p) ov[p] = __shfl_xor(tv[p], off, 64);
        #pragma unroll
        for (int p = 0; p < TOPK; ++p) {
            float v = ov[p];
            if (v > tv[TOPK - 1]) {
                tv[TOPK - 1] = v;
                #pragma unroll
                for (int p2 = TOPK - 1; p2 > 0; --p2) {
                    if (tv[p2] > tv[p2 - 1]) { float a = tv[p2]; tv[p2] = tv[p2 - 1]; tv[p2 - 1] = a; }
                }
            }
        }
    }
    if (lane == 0) {
        #pragma unroll
        for (int p = 0; p < TOPK; ++p) wtop[wave][p] = tv[p];
    }
    if (t == 0) ccnt = 0;
    __syncthreads();
    if (t == 0) {
        float fv[TOPK];
        #pragma unroll
        for (int p = 0; p < TOPK; ++p) fv[p] = wtop[0][p];
        for (int w = 1; w < 4; ++w) {
            #pragma unroll
            for (int p = 0; p < TOPK; ++p) {
                float v = wtop[w][p];
                if (v > fv[TOPK - 1]) {
                    fv[TOPK - 1] = v;
                    #pragma unroll
                    for (int p2 = TOPK - 1; p2 > 0; --p2) {
                        if (fv[p2] > fv[p2 - 1]) { float a = fv[p2]; fv[p2] = fv[p2 - 1]; fv[p2 - 1] = a; }
                    }
                }
            }
        }
        v5s = fv[TOPK - 1];
    }
    qs[t] = qn[b * DIM + t];
    __syncthreads();

    // ---- phase 2: collect candidates >= v5 - DELTA (superset of true top5) ----
    float thr = v5s - DELTA;
    for (int m = t; m < NC; m += 256) {
        if (cv[m] >= thr) {
            int pos = atomicAdd(&ccnt, 1);
            if (pos < MAXC) clist[pos] = ci[m];
        }
    }
    __syncthreads();
    int cnt = min(ccnt, MAXC);

    // ---- phase 3: exact fp32 rescore (one wave per candidate) ----
    for (int c = wave; c < cnt; c += 4) {
        const float4 k4 = *(const float4*)(keys + (size_t)clist[c] * DIM + lane * 4);
        const float4 q4 = *(const float4*)(qs + lane * 4);
        float d  = q4.x * k4.x + q4.y * k4.y + q4.z * k4.z + q4.w * k4.w;
        float s2 = k4.x * k4.x + k4.y * k4.y + k4.z * k4.z + k4.w * k4.w;
        #pragma unroll
        for (int off = 1; off < 64; off <<= 1) {
            d  += __shfl_xor(d, off, 64);
            s2 += __shfl_xor(s2, off, 64);
        }
        if (lane == 0) rsc[c] = d * rsqrtf(fmaxf(s2, 1e-24f));
    }
    __syncthreads();

    // ---- phase 4: rank-based exact top-5 ((value, key-index) order) ----
    if (t < cnt) {
        float myv = rsc[t]; int myk = clist[t];
        int rank = 0;
        for (int c = 0; c < cnt; ++c) {
            float v = rsc[c];
            if (v > myv || (v == myv && clist[c] < myk)) ++rank;
        }
        if (rank < TOPK) kidx[rank] = myk;
    }
    __syncthreads();

    // ---- phase 5: gather values + mean; scatter counts ----
    float s = 0.f;
    #pragma unroll
    for (int p = 0; p < TOPK; ++p) s += values[(size_t)kidx[p] * DIM + t];
    outRet[b * DIM + t] = s * 0.2f;
    if (t < TOPK) atomicAdd(&outCnt[kidx[t]], 1.0f);
}

// ---------------- launch -----------------------------------------------------
extern "C" void kernel_launch(void* const* d_in, const int* in_sizes, int n_in,
                              void* d_out, int out_size, void* d_ws, size_t ws_size,
                              hipStream_t stream) {
    const float* query  = (const float*)d_in[0];
    const float* keys   = (const float*)d_in[1];
    const float* values = (const float*)d_in[2];
    const float* acnt   = (const float*)d_in[3];
    float* outRet = (float*)d_out;
    float* outCnt = outRet + NQ * DIM;

    char* ws = (char*)d_ws;
    float* qn    = (float*)ws;                                   // 64 KB
    float* qpart = (float*)(ws + 65536);                         // 256 KB
    float* candV = (float*)(ws + 65536 + 262144);                // 1.25 MB
    int*   candI = (int*)(ws + 65536 + 262144 + (size_t)NQ * NC * 4);

    qmean_part_kernel<<<256, 256, 0, stream>>>(query, acnt, qpart, outCnt);
    qmean_norm2_kernel<<<NQ, 256, 0, stream>>>(qpart, qn);
    sims_mfma_topk<<<NBLK, 256, 0, stream>>>(keys, qn, candV, candI);
    finalize_kernel<<<NQ, 256, 0, stream>>>(candV, candI, keys, qn, values,
                                            outRet, outCnt);
}